// Round 3
// baseline (9151.028 us; speedup 1.0000x reference)
//
#include <hip/hip_runtime.h>
#include <hip/hip_cooperative_groups.h>

namespace cg = cooperative_groups;

// ConvLSTM1D: B=8, T=128, CIN=64, COUT=64, H=256
// R3: ONE persistent cooperative kernel; t-loop inside with grid.sync().
//  - weights staged to LDS once (48 KB/block: this block's 32 conv rows),
//    read per-step as wave-uniform broadcast ds_read_b128
//  - bias / wci / wcf / wco / running c-state live in registers across steps
//  - cat (input+h) staged to LDS per step, [p][ic] XOR-swizzled for b128 reads
//  - hs doubles as the h recurrent buffer; cs is a pure output stream
// Grid 256 blocks (1/CU), 256 threads. Block = (b, p-chunk of 64, co-chunk of 8).
// blockIdx swizzle co-locates the 8 co-chunks of one (b,p-chunk) on one XCD.

constexpr int Bn    = 8;
constexpr int Tn    = 128;
constexpr int CINn  = 64;
constexpr int COUTn = 64;
constexpr int Hn    = 256;
constexpr int ICAT  = CINn + COUTn;   // 128
constexpr int PP    = 64;             // p positions per block

__device__ __forceinline__ float sigmoidf_(float v) {
    return 1.0f / (1.0f + __expf(-v));
}

__global__ __launch_bounds__(256, 1) void convlstm_persist(
    const float* __restrict__ x,     // [B][T][CIN][H]
    const float* __restrict__ h0,    // [B][COUT][H]
    const float* __restrict__ c0,    // [B][COUT][H]
    const float* __restrict__ wg,    // [4*COUT][ICAT][3]
    const float* __restrict__ bias,  // [4*COUT]
    const float* __restrict__ wci,   // [COUT][H]
    const float* __restrict__ wcf,   // [COUT][H]
    const float* __restrict__ wco,   // [COUT][H]
    float* __restrict__ hs,          // [B][T][COUT][H]
    float* __restrict__ cs)          // [B][T][COUT][H]
{
    __shared__ float wlds[32 * 384];      // 48 KB: this block's weight rows
    __shared__ float cat[66 * 128];       // 33.8 KB, [p][ic] swizzled
    __shared__ float conv_out[32 * 64];   // 8 KB

    const int tid = threadIdx.x;
    // swizzled block decode: blk = (gid%8) + 8*coz + 64*(gid/8)
    const int blk = blockIdx.x;
    const int coz = (blk >> 3) & 7;                  // co-chunk 0..7
    const int gid = ((blk >> 6) << 3) + (blk & 7);   // 0..31 = (b, p-chunk)
    const int b   = gid >> 2;
    const int p0  = (gid & 3) * PP;

    const int p_l = tid & 63;
    const int icg = tid >> 6;                        // 0..3
    const int wv  = __builtin_amdgcn_readfirstlane(tid >> 6);

    // ---- one-time: weights -> LDS ----
    // local row lr = gate*8 + k  <->  global row gate*64 + coz*8 + k
    for (int f = tid; f < 32 * 384; f += 256) {
        const int lr = f / 384;
        const int j  = f - lr * 384;
        const int grow = (lr >> 3) * COUTn + coz * 8 + (lr & 7);
        wlds[f] = wg[(size_t)grow * (ICAT * 3) + j];
    }

    // ---- one-time: per-thread persistent registers ----
    float bias_r[8];
#pragma unroll
    for (int k = 0; k < 8; ++k)
        bias_r[k] = bias[wv * COUTn + coz * 8 + k];

    const int pg = p0 + p_l;
    float c_reg[2], wci_r[2], wcf_r[2], wco_r[2];
#pragma unroll
    for (int j = 0; j < 2; ++j) {
        const int co = coz * 8 + wv * 2 + j;
        const size_t cidx = (size_t)co * Hn + pg;
        wci_r[j] = wci[cidx];
        wcf_r[j] = wcf[cidx];
        wco_r[j] = wco[cidx];
        c_reg[j] = c0[(size_t)b * COUTn * Hn + cidx];
    }

    cg::grid_group grid = cg::this_grid();

    for (int t = 0; t < Tn; ++t) {
        const float* xt = x + (size_t)(b * Tn + t) * CINn * Hn;
        const float* hp = (t == 0)
            ? (h0 + (size_t)b * COUTn * Hn)
            : (hs + (size_t)(b * Tn + (t - 1)) * COUTn * Hn);

        // ---- stage cat into LDS (transposed + swizzled) ----
        {
            float vx[16], vh[16];
#pragma unroll
            for (int icc = 0; icc < 16; ++icc)
                vx[icc] = xt[(size_t)(icc * 4 + icg) * Hn + pg];
#pragma unroll
            for (int icc = 0; icc < 16; ++icc)
                vh[icc] = hp[(size_t)(icc * 4 + icg) * Hn + pg];

            const int row = p_l + 1;
#pragma unroll
            for (int icc = 0; icc < 16; ++icc) {
                const int ic   = icc * 4 + icg;
                const int slot = (ic >> 2) ^ (row & 31);
                cat[row * 128 + slot * 4 + (ic & 3)] = vx[icc];
            }
#pragma unroll
            for (int icc = 0; icc < 16; ++icc) {
                const int ic   = (icc + 16) * 4 + icg;
                const int slot = (ic >> 2) ^ (row & 31);
                cat[row * 128 + slot * 4 + (ic & 3)] = vh[icc];
            }
            // halo rows 0 and 65
            if (tid < 128) {
                const int ic = tid;
                float v = 0.0f;
                if (p0 > 0) {
                    const float* src = (ic < CINn)
                        ? (xt + (size_t)ic * Hn)
                        : (hp + (size_t)(ic - CINn) * Hn);
                    v = src[p0 - 1];
                }
                cat[(ic >> 2) * 4 + (ic & 3)] = v;              // row 0, ^0
            } else {
                const int ic = tid - 128;
                float v = 0.0f;
                if (p0 + PP < Hn) {
                    const float* src = (ic < CINn)
                        ? (xt + (size_t)ic * Hn)
                        : (hp + (size_t)(ic - CINn) * Hn);
                    v = src[p0 + PP];
                }
                const int slot = (ic >> 2) ^ 1;                 // row 65: 65&31=1
                cat[65 * 128 + slot * 4 + (ic & 3)] = v;
            }
        }
        __syncthreads();

        // ---- GEMM: wave wv = gate; rows lr = wv*8+k; weights from LDS ----
        float acc[8];
#pragma unroll
        for (int k = 0; k < 8; ++k) acc[k] = bias_r[k];

        const float4* cat4 = (const float4*)cat;
        const float4* w4   = (const float4*)wlds;
        const int r0 = p_l, r1 = p_l + 1, r2 = p_l + 2;
        const int s0 = r0 & 31, s1 = r1 & 31, s2 = r2 & 31;

#pragma unroll 2
        for (int icq = 0; icq < 32; ++icq) {
            const float4 a0 = cat4[r0 * 32 + (icq ^ s0)];
            const float4 a1 = cat4[r1 * 32 + (icq ^ s1)];
            const float4 a2 = cat4[r2 * 32 + (icq ^ s2)];
            const float in0[4] = {a0.x, a0.y, a0.z, a0.w};
            const float in1[4] = {a1.x, a1.y, a1.z, a1.w};
            const float in2[4] = {a2.x, a2.y, a2.z, a2.w};
#pragma unroll
            for (int k = 0; k < 8; ++k) {
                const int base = (((wv * 8 + k) * 384 + icq * 12) >> 2);
                const float4 w0 = w4[base];
                const float4 w1 = w4[base + 1];
                const float4 w2 = w4[base + 2];
                const float wr_[12] = {w0.x, w0.y, w0.z, w0.w,
                                       w1.x, w1.y, w1.z, w1.w,
                                       w2.x, w2.y, w2.z, w2.w};
#pragma unroll
                for (int i = 0; i < 4; ++i) {
                    acc[k] = fmaf(wr_[3 * i + 0], in0[i],
                              fmaf(wr_[3 * i + 1], in1[i],
                              fmaf(wr_[3 * i + 2], in2[i], acc[k])));
                }
            }
        }

#pragma unroll
        for (int k = 0; k < 8; ++k)
            conv_out[(wv * 8 + k) * 64 + p_l] = acc[k];
        __syncthreads();

        // ---- gates: thread handles co_l = wv*2+{0,1}; c kept in regs ----
#pragma unroll
        for (int j = 0; j < 2; ++j) {
            const int co_l = wv * 2 + j;
            const float pi  = conv_out[(0 * 8 + co_l) * 64 + p_l];
            const float pf  = conv_out[(1 * 8 + co_l) * 64 + p_l];
            const float pgg = conv_out[(2 * 8 + co_l) * 64 + p_l];
            const float po  = conv_out[(3 * 8 + co_l) * 64 + p_l];

            const float cprev = c_reg[j];
            const float iv = sigmoidf_(pi + wci_r[j] * cprev);
            const float fv = sigmoidf_(pf + wcf_r[j] * cprev);
            const float gv = tanhf(pgg);
            const float cn = fv * cprev + iv * gv;
            const float ov = sigmoidf_(po + wco_r[j] * cn);
            const float hn = ov * tanhf(cn);
            c_reg[j] = cn;

            const int co = coz * 8 + co_l;
            const size_t oidx = ((size_t)(b * Tn + t) * COUTn + co) * Hn + pg;
            hs[oidx] = hn;
            cs[oidx] = cn;
        }

        __threadfence();   // make hs stores device-visible before next stage
        grid.sync();
    }
}

extern "C" void kernel_launch(void* const* d_in, const int* in_sizes, int n_in,
                              void* d_out, int out_size, void* d_ws, size_t ws_size,
                              hipStream_t stream) {
    (void)in_sizes; (void)n_in; (void)out_size; (void)d_ws; (void)ws_size;

    const float* x    = (const float*)d_in[0];
    const float* h0   = (const float*)d_in[1];
    const float* c0   = (const float*)d_in[2];
    const float* w    = (const float*)d_in[3];
    const float* bias = (const float*)d_in[4];
    const float* wci  = (const float*)d_in[5];
    const float* wcf  = (const float*)d_in[6];
    const float* wco  = (const float*)d_in[7];

    float* hs = (float*)d_out;
    float* cs = hs + (size_t)Bn * Tn * COUTn * Hn;

    void* args[] = {(void*)&x, (void*)&h0, (void*)&c0, (void*)&w,
                    (void*)&bias, (void*)&wci, (void*)&wcf, (void*)&wco,
                    (void*)&hs, (void*)&cs};
    hipLaunchCooperativeKernel((const void*)convlstm_persist,
                               dim3(256), dim3(256), args, 0, stream);
}

// Round 4
// 4671.102 us; speedup vs baseline: 1.9591x; 1.9591x over previous
//
#include <hip/hip_runtime.h>
#include <hip/hip_cooperative_groups.h>

namespace cg = cooperative_groups;

// ConvLSTM1D: B=8, T=128, CIN=64, COUT=64, H=256
// R4: persistent kernel, distributed flag sync (no grid.sync), weights via
// wave-uniform global loads (scalar pipe), conflict-free b128 LDS staging.
// Block = (b, p-chunk of 64, co-chunk of 8), 256 blocks x 256 threads.
// d_out doubles as recurrent h storage; c stays in registers.

constexpr int Bn    = 8;
constexpr int Tn    = 128;
constexpr int CINn  = 64;
constexpr int COUTn = 64;
constexpr int Hn    = 256;
constexpr int ICAT  = CINn + COUTn;   // 128
constexpr int PP    = 64;
constexpr int NPC   = Hn / PP;        // 4 p-chunks
constexpr int NCOZ  = 8;              // co-chunk producers per (b,pc)

__device__ __forceinline__ float sigmoidf_(float v) {
    return 1.0f / (1.0f + __expf(-v));
}

template <bool USE_FLAGS>
__global__ __launch_bounds__(256, 1) void convlstm_persist(
    const float* __restrict__ x,     // [B][T][CIN][H]
    const float* __restrict__ h0,    // [B][COUT][H]
    const float* __restrict__ c0,    // [B][COUT][H]
    const float* __restrict__ wg,    // [4*COUT][ICAT][3]
    const float* __restrict__ bias,  // [4*COUT]
    const float* __restrict__ wci,   // [COUT][H]
    const float* __restrict__ wcf,   // [COUT][H]
    const float* __restrict__ wco,   // [COUT][H]
    float* __restrict__ hs,          // [B][T][COUT][H]
    float* __restrict__ cs,          // [B][T][COUT][H]
    int* flags)                      // [B][NPC][T] producer counters
{
    __shared__ float cat[66 * 128];       // [row(p)][ic], quad-swizzled
    __shared__ float conv_out[32 * 64];

    const int tid = threadIdx.x;
    // XCD-grouping swizzle: 8 coz-blocks of one (b,pc) share blk%8 -> one XCD
    const int blk = blockIdx.x;
    const int coz = (blk >> 3) & 7;
    const int gid = ((blk >> 6) << 3) + (blk & 7);   // 0..31 = b*4+pc
    const int b   = gid >> 2;
    const int pc  = gid & 3;
    const int p0  = pc * PP;

    const int p_l = tid & 63;
    const int icg = tid >> 6;
    const int wv  = __builtin_amdgcn_readfirstlane(tid >> 6);
    const int pg  = p0 + p_l;

    // persistent per-thread state
    float bias_r[8];
#pragma unroll
    for (int k = 0; k < 8; ++k) bias_r[k] = bias[wv * COUTn + coz * 8 + k];

    float c_reg[2], wci_r[2], wcf_r[2], wco_r[2];
#pragma unroll
    for (int j = 0; j < 2; ++j) {
        const int co = coz * 8 + wv * 2 + j;
        const size_t cidx = (size_t)co * Hn + pg;
        wci_r[j] = wci[cidx];
        wcf_r[j] = wcf[cidx];
        wco_r[j] = wco[cidx];
        c_reg[j] = c0[(size_t)b * COUTn * Hn + cidx];
    }

    // wave-uniform weight base (blockIdx/readfirstlane-derived -> s_load)
    const int chan0 = wv * COUTn + coz * 8;
    const float4* __restrict__ w4 =
        (const float4*)(wg + (size_t)chan0 * (ICAT * 3));

    cg::grid_group grid = cg::this_grid();

    const int row = p_l + 1;        // local cat row for own p
    const int rs  = row & 31;
    float4* cat4v = (float4*)cat;

    for (int t = 0; t < Tn; ++t) {
        const float* xt = x + (size_t)(b * Tn + t) * CINn * Hn;
        const float* hp = (t == 0)
            ? (h0 + (size_t)b * COUTn * Hn)
            : (hs + (size_t)(b * Tn + (t - 1)) * COUTn * Hn);

        // ---- x quads: issue before the spin (no dependency) ----
        float4 qx[4];
#pragma unroll
        for (int j = 0; j < 4; ++j) {
            const int q = icg + 4 * j;                 // quads 0..15 = x
            const float* s = xt + (size_t)(4 * q) * Hn + pg;
            qx[j].x = s[0]; qx[j].y = s[Hn]; qx[j].z = s[2 * Hn]; qx[j].w = s[3 * Hn];
        }

        // ---- wait for h_{t-1} producers (own chunk + halo neighbors) ----
        if (USE_FLAGS && t > 0) {
            const int lo = (pc > 0) ? pc - 1 : pc;
            const int hi = (pc < NPC - 1) ? pc + 1 : pc;
            bool ok = false;
            while (!ok) {
                ok = true;
                for (int n = lo; n <= hi; ++n)
                    ok &= (__hip_atomic_load(&flags[(b * NPC + n) * Tn + (t - 1)],
                                             __ATOMIC_RELAXED,
                                             __HIP_MEMORY_SCOPE_AGENT) >= NCOZ);
                if (!ok) __builtin_amdgcn_s_sleep(4);
            }
            __builtin_amdgcn_fence(__ATOMIC_ACQUIRE, "agent");
        }

        // ---- h quads, then all b128 LDS writes (conflict-free) ----
        {
            float4 qh[4];
#pragma unroll
            for (int j = 0; j < 4; ++j) {
                const int q = icg + 4 * (j + 4);       // quads 16..31 = h
                const float* s = hp + (size_t)(4 * q - CINn) * Hn + pg;
                qh[j].x = s[0]; qh[j].y = s[Hn]; qh[j].z = s[2 * Hn]; qh[j].w = s[3 * Hn];
            }
#pragma unroll
            for (int j = 0; j < 4; ++j)
                cat4v[row * 32 + ((icg + 4 * j) ^ rs)] = qx[j];
#pragma unroll
            for (int j = 0; j < 4; ++j)
                cat4v[row * 32 + ((icg + 4 * (j + 4)) ^ rs)] = qh[j];
        }

        // ---- halo rows 0 (p0-1) and 65 (p0+64) ----
        if (tid < 128) {
            const int ic = tid;
            float v = 0.0f;
            if (p0 > 0) {
                const float* s = (ic < CINn) ? (xt + (size_t)ic * Hn)
                                             : (hp + (size_t)(ic - CINn) * Hn);
                v = s[p0 - 1];
            }
            cat[(ic >> 2) * 4 + (ic & 3)] = v;                       // row 0: ^0
        } else {
            const int ic = tid - 128;
            float v = 0.0f;
            if (p0 + PP < Hn) {
                const float* s = (ic < CINn) ? (xt + (size_t)ic * Hn)
                                             : (hp + (size_t)(ic - CINn) * Hn);
                v = s[p0 + PP];
            }
            cat[65 * 128 + (((ic >> 2) ^ 1) << 2) + (ic & 3)] = v;   // row 65: ^1
        }
        __syncthreads();

        // ---- GEMM: 8 rows x 384 K per thread; weights via s_load ----
        float acc[8];
#pragma unroll
        for (int k = 0; k < 8; ++k) acc[k] = bias_r[k];

        const float4* cat4 = (const float4*)cat;
        const int r0 = p_l, r1 = p_l + 1, r2 = p_l + 2;
        const int s0 = r0 & 31, s1 = r1 & 31, s2 = r2 & 31;

#pragma unroll 4
        for (int icq = 0; icq < 32; ++icq) {
            const float4 a0 = cat4[r0 * 32 + (icq ^ s0)];
            const float4 a1 = cat4[r1 * 32 + (icq ^ s1)];
            const float4 a2 = cat4[r2 * 32 + (icq ^ s2)];
            const float in0[4] = {a0.x, a0.y, a0.z, a0.w};
            const float in1[4] = {a1.x, a1.y, a1.z, a1.w};
            const float in2[4] = {a2.x, a2.y, a2.z, a2.w};
#pragma unroll
            for (int k = 0; k < 8; ++k) {
                const float4 w0 = w4[k * 96 + icq * 3 + 0];
                const float4 w1 = w4[k * 96 + icq * 3 + 1];
                const float4 w2 = w4[k * 96 + icq * 3 + 2];
                const float wr_[12] = {w0.x, w0.y, w0.z, w0.w,
                                       w1.x, w1.y, w1.z, w1.w,
                                       w2.x, w2.y, w2.z, w2.w};
#pragma unroll
                for (int i = 0; i < 4; ++i) {
                    acc[k] = fmaf(wr_[3 * i + 0], in0[i],
                              fmaf(wr_[3 * i + 1], in1[i],
                              fmaf(wr_[3 * i + 2], in2[i], acc[k])));
                }
            }
        }

#pragma unroll
        for (int k = 0; k < 8; ++k)
            conv_out[(wv * 8 + k) * 64 + p_l] = acc[k];
        __syncthreads();

        // ---- gates; c in registers; coalesced stores ----
#pragma unroll
        for (int j = 0; j < 2; ++j) {
            const int co_l = wv * 2 + j;
            const float pi  = conv_out[(0 * 8 + co_l) * 64 + p_l];
            const float pf  = conv_out[(1 * 8 + co_l) * 64 + p_l];
            const float pgv = conv_out[(2 * 8 + co_l) * 64 + p_l];
            const float po  = conv_out[(3 * 8 + co_l) * 64 + p_l];

            const float cprev = c_reg[j];
            const float iv = sigmoidf_(pi + wci_r[j] * cprev);
            const float fv = sigmoidf_(pf + wcf_r[j] * cprev);
            const float gv = tanhf(pgv);
            const float cn = fv * cprev + iv * gv;
            const float ov = sigmoidf_(po + wco_r[j] * cn);
            const float hn = ov * tanhf(cn);
            c_reg[j] = cn;

            const int co = coz * 8 + co_l;
            const size_t oidx = ((size_t)(b * Tn + t) * COUTn + co) * Hn + pg;
            hs[oidx] = hn;
            cs[oidx] = cn;
        }
        __syncthreads();   // drains all waves' stores (vmcnt 0) before flag

        if (USE_FLAGS) {
            if (tid == 0) {
                __threadfence();   // release: flush h/c stores toward L3
                atomicAdd(&flags[(b * NPC + pc) * Tn + t], 1);
            }
        } else {
            __threadfence();
            grid.sync();
        }
    }
}

extern "C" void kernel_launch(void* const* d_in, const int* in_sizes, int n_in,
                              void* d_out, int out_size, void* d_ws, size_t ws_size,
                              hipStream_t stream) {
    (void)in_sizes; (void)n_in; (void)out_size;

    const float* x    = (const float*)d_in[0];
    const float* h0   = (const float*)d_in[1];
    const float* c0   = (const float*)d_in[2];
    const float* w    = (const float*)d_in[3];
    const float* bias = (const float*)d_in[4];
    const float* wci  = (const float*)d_in[5];
    const float* wcf  = (const float*)d_in[6];
    const float* wco  = (const float*)d_in[7];

    float* hs = (float*)d_out;
    float* cs = hs + (size_t)Bn * Tn * COUTn * Hn;
    int* flags = (int*)d_ws;

    const size_t flag_bytes = (size_t)Bn * NPC * Tn * sizeof(int);  // 16 KB
    const bool use_flags = (d_ws != nullptr) && (ws_size >= flag_bytes);

    void* args[] = {(void*)&x, (void*)&h0, (void*)&c0, (void*)&w,
                    (void*)&bias, (void*)&wci, (void*)&wcf, (void*)&wco,
                    (void*)&hs, (void*)&cs, (void*)&flags};

    if (use_flags) {
        hipMemsetAsync(d_ws, 0, flag_bytes, stream);
        hipLaunchCooperativeKernel((const void*)convlstm_persist<true>,
                                   dim3(256), dim3(256), args, 0, stream);
    } else {
        hipLaunchCooperativeKernel((const void*)convlstm_persist<false>,
                                   dim3(256), dim3(256), args, 0, stream);
    }
}

// Round 5
// 3670.093 us; speedup vs baseline: 2.4934x; 1.2727x over previous
//
#include <hip/hip_runtime.h>
#include <hip/hip_cooperative_groups.h>

namespace cg = cooperative_groups;

// ConvLSTM1D: B=8, T=128, CIN=64, COUT=64, H=256
// R5: persistent cooperative kernel, new geometry:
//   block = (b, coz of 2 output channels) x ALL H=256 positions (lane = p).
//   grid = 8*32 = 256 blocks, 256 threads.
//   - weights: 12 KB/block, block-uniform global float4 -> s_load, scalar-$-resident
//   - gate math thread-local (thread owns i,f,g,o for 2 co at its p)
//   - h/c/flags: system-scope relaxed atomics (sc0 sc1 write-through to L3).
//     NO agent acquire fences -> L2 stays warm with weights/x across steps.
//   - cat [258 rows(p)][128 ic] fp32 in 132 KB dynamic LDS, XOR-swizzled b128.
//   - flags[b][t][coz] = t+1 when (b,coz) finished step t; consumers poll the
//     32 words of (b,t-1). Flag zeroing via write-through kernel (replay-safe).

constexpr int Bn    = 8;
constexpr int Tn    = 128;
constexpr int CINn  = 64;
constexpr int COUTn = 64;
constexpr int Hn    = 256;
constexpr int NCOZ  = 32;                       // co-chunks of 2
constexpr int NFLAG = Bn * Tn * NCOZ;           // 32768 words
constexpr size_t LDS_BYTES = (size_t)258 * 128 * 4;  // 132096

__device__ __forceinline__ float sigmoidf_(float v) {
    return 1.0f / (1.0f + __expf(-v));
}

__device__ __forceinline__ float load_thru(const float* p) {
    return __hip_atomic_load(p, __ATOMIC_RELAXED, __HIP_MEMORY_SCOPE_SYSTEM);
}
__device__ __forceinline__ void store_thru(float* p, float v) {
    __hip_atomic_store(p, v, __ATOMIC_RELAXED, __HIP_MEMORY_SCOPE_SYSTEM);
}

template <bool USE_FLAGS>
__global__ __launch_bounds__(256, 1) void convlstm_persist(
    const float* __restrict__ x,     // [B][T][CIN][H]
    const float* __restrict__ h0,    // [B][COUT][H]
    const float* __restrict__ c0,    // [B][COUT][H]
    const float* __restrict__ wg,    // [4*COUT][128][3]
    const float* __restrict__ bias,  // [4*COUT]
    const float* __restrict__ wci,   // [COUT][H]
    const float* __restrict__ wcf,   // [COUT][H]
    const float* __restrict__ wco,   // [COUT][H]
    float* __restrict__ hs,          // [B][T][COUT][H]
    float* __restrict__ cs,          // [B][T][COUT][H]
    unsigned int* flags)             // [B][T][NCOZ]
{
    extern __shared__ float cat[];            // [258][128], swizzled
    float4* cat4 = (float4*)cat;

    const int tid = threadIdx.x;
    const int blk = blockIdx.x;
    const int b   = blk & 7;                  // XCD affinity (heuristic only)
    const int coz = blk >> 3;                 // 0..31
    const int p   = tid;                      // lane = spatial position
    const int co0 = coz * 2;

    // zero SAME-padding halo rows (0 and 257) once; t-invariant
    if (tid < 32)       cat4[tid] = make_float4(0.f, 0.f, 0.f, 0.f);
    else if (tid < 64)  cat4[257 * 32 + (tid - 32)] = make_float4(0.f, 0.f, 0.f, 0.f);

    // persistent registers
    float bias_r[8];
#pragma unroll
    for (int k = 0; k < 8; ++k)
        bias_r[k] = bias[(k >> 1) * COUTn + co0 + (k & 1)];

    float c_reg[2], wci_r[2], wcf_r[2], wco_r[2];
#pragma unroll
    for (int j = 0; j < 2; ++j) {
        const int cidx = (co0 + j) * Hn + p;
        wci_r[j] = wci[cidx];
        wcf_r[j] = wcf[cidx];
        wco_r[j] = wco[cidx];
        c_reg[j] = c0[b * COUTn * Hn + cidx];
    }

    const float4* __restrict__ w4 = (const float4*)wg;  // block-uniform rows

    cg::grid_group grid = cg::this_grid();

    const int r0 = tid, r1 = tid + 1, r2 = tid + 2;
    const int s0 = r0 & 31, s1 = r1 & 31, s2 = r2 & 31;

    for (int t = 0; t < Tn; ++t) {
        const float* xt = x + (size_t)(b * Tn + t) * CINn * Hn;
        const float* hp = (t == 0)
            ? (h0 + (size_t)b * COUTn * Hn)
            : (hs + (size_t)(b * Tn + (t - 1)) * COUTn * Hn);

        // ---- stage x (independent of recurrence) ----
        float vx[64];
#pragma unroll
        for (int ic = 0; ic < CINn; ++ic) vx[ic] = xt[ic * Hn + p];
#pragma unroll
        for (int i = 0; i < 16; ++i)
            cat4[r1 * 32 + (i ^ s1)] =
                make_float4(vx[4 * i], vx[4 * i + 1], vx[4 * i + 2], vx[4 * i + 3]);

        // ---- wait for h_{t-1} producers (all 32 coz of batch b) ----
        if (USE_FLAGS && t > 0) {
            const unsigned int* fptr =
                flags + ((size_t)(b * Tn + (t - 1)) * NCOZ) + (tid & 31);
            const unsigned int want = (unsigned int)t;  // producer wrote t at step t-1? no: t-1+1 = t
            while (true) {
                unsigned int v = __hip_atomic_load(fptr, __ATOMIC_RELAXED,
                                                   __HIP_MEMORY_SCOPE_SYSTEM);
                if (__all(v == want)) break;
                __builtin_amdgcn_s_sleep(2);
            }
        }

        // ---- stage h (write-through reads: L3-coherent, poison-immune) ----
        float vh[64];
#pragma unroll
        for (int hc = 0; hc < COUTn; ++hc) vh[hc] = load_thru(hp + hc * Hn + p);
#pragma unroll
        for (int i = 0; i < 16; ++i)
            cat4[r1 * 32 + ((16 + i) ^ s1)] =
                make_float4(vh[4 * i], vh[4 * i + 1], vh[4 * i + 2], vh[4 * i + 3]);

        __syncthreads();   // cat ready (also orders halo zeroing at t=0)

        // ---- GEMM: 8 rows (4 gates x 2 co) x K=384; weights via s_load ----
        float acc[8];
#pragma unroll
        for (int k = 0; k < 8; ++k) acc[k] = bias_r[k];

#pragma unroll 4
        for (int icq = 0; icq < 32; ++icq) {
            const float4 a0 = cat4[r0 * 32 + (icq ^ s0)];
            const float4 a1 = cat4[r1 * 32 + (icq ^ s1)];
            const float4 a2 = cat4[r2 * 32 + (icq ^ s2)];
            const float in0[4] = {a0.x, a0.y, a0.z, a0.w};
            const float in1[4] = {a1.x, a1.y, a1.z, a1.w};
            const float in2[4] = {a2.x, a2.y, a2.z, a2.w};
#pragma unroll
            for (int k = 0; k < 8; ++k) {
                const int row = (k >> 1) * COUTn + co0 + (k & 1);
                const float4 w0 = w4[(size_t)row * 96 + icq * 3 + 0];
                const float4 w1 = w4[(size_t)row * 96 + icq * 3 + 1];
                const float4 w2 = w4[(size_t)row * 96 + icq * 3 + 2];
                const float wr_[12] = {w0.x, w0.y, w0.z, w0.w,
                                       w1.x, w1.y, w1.z, w1.w,
                                       w2.x, w2.y, w2.z, w2.w};
#pragma unroll
                for (int i = 0; i < 4; ++i) {
                    acc[k] = fmaf(wr_[3 * i + 0], in0[i],
                              fmaf(wr_[3 * i + 1], in1[i],
                              fmaf(wr_[3 * i + 2], in2[i], acc[k])));
                }
            }
        }

        // ---- gates: fully thread-local; stores write-through ----
#pragma unroll
        for (int j = 0; j < 2; ++j) {
            const float pi  = acc[0 + j];
            const float pf  = acc[2 + j];
            const float pgv = acc[4 + j];
            const float po  = acc[6 + j];

            const float cprev = c_reg[j];
            const float iv = sigmoidf_(pi + wci_r[j] * cprev);
            const float fv = sigmoidf_(pf + wcf_r[j] * cprev);
            const float gv = tanhf(pgv);
            const float cn = fv * cprev + iv * gv;
            const float ov = sigmoidf_(po + wco_r[j] * cn);
            const float hn = ov * tanhf(cn);
            c_reg[j] = cn;

            const int co = co0 + j;
            const size_t oidx = ((size_t)(b * Tn + t) * COUTn + co) * Hn + p;
            store_thru(hs + oidx, hn);
            store_thru(cs + oidx, cn);
        }

        if (USE_FLAGS) {
            __syncthreads();   // waits vmcnt(0): all waves' h/c stores at L3
            if (tid == 0) {
                __hip_atomic_store(flags + (size_t)(b * Tn + t) * NCOZ + coz,
                                   (unsigned int)(t + 1), __ATOMIC_RELAXED,
                                   __HIP_MEMORY_SCOPE_SYSTEM);
            }
        } else {
            __threadfence();
            grid.sync();
        }
    }
}

__global__ __launch_bounds__(256) void zero_flags(unsigned int* f, int n) {
    const int i = blockIdx.x * 256 + threadIdx.x;
    if (i < n)
        __hip_atomic_store(&f[i], 0u, __ATOMIC_RELAXED, __HIP_MEMORY_SCOPE_SYSTEM);
}

extern "C" void kernel_launch(void* const* d_in, const int* in_sizes, int n_in,
                              void* d_out, int out_size, void* d_ws, size_t ws_size,
                              hipStream_t stream) {
    (void)in_sizes; (void)n_in; (void)out_size;

    const float* x    = (const float*)d_in[0];
    const float* h0   = (const float*)d_in[1];
    const float* c0   = (const float*)d_in[2];
    const float* w    = (const float*)d_in[3];
    const float* bias = (const float*)d_in[4];
    const float* wci  = (const float*)d_in[5];
    const float* wcf  = (const float*)d_in[6];
    const float* wco  = (const float*)d_in[7];

    float* hs = (float*)d_out;
    float* cs = hs + (size_t)Bn * Tn * COUTn * Hn;
    unsigned int* flags = (unsigned int*)d_ws;

    const size_t flag_bytes = (size_t)NFLAG * sizeof(unsigned int);  // 128 KB
    const bool use_flags = (d_ws != nullptr) && (ws_size >= flag_bytes);

    void* args[] = {(void*)&x, (void*)&h0, (void*)&c0, (void*)&w,
                    (void*)&bias, (void*)&wci, (void*)&wcf, (void*)&wco,
                    (void*)&hs, (void*)&cs, (void*)&flags};

    if (use_flags) {
        hipFuncSetAttribute((const void*)convlstm_persist<true>,
                            hipFuncAttributeMaxDynamicSharedMemorySize,
                            (int)LDS_BYTES);
        zero_flags<<<(NFLAG + 255) / 256, 256, 0, stream>>>(flags, NFLAG);
        hipLaunchCooperativeKernel((const void*)convlstm_persist<true>,
                                   dim3(256), dim3(256), args,
                                   (unsigned int)LDS_BYTES, stream);
    } else {
        hipFuncSetAttribute((const void*)convlstm_persist<false>,
                            hipFuncAttributeMaxDynamicSharedMemorySize,
                            (int)LDS_BYTES);
        hipLaunchCooperativeKernel((const void*)convlstm_persist<false>,
                                   dim3(256), dim3(256), args,
                                   (unsigned int)LDS_BYTES, stream);
    }
}

// Round 6
// 3530.995 us; speedup vs baseline: 2.5916x; 1.0394x over previous
//
#include <hip/hip_runtime.h>
#include <hip/hip_cooperative_groups.h>

namespace cg = cooperative_groups;

// ConvLSTM1D: B=8, T=128, CIN=64, COUT=64, H=256
// R6: persistent kernel, x/h wave-specialization.
// Block = (b, coz of 2 co) x all 256 p; 512 threads; grid 256 (1 block/CU).
//   waves 0-3 (kh=0): x-half of K (ic 0..63)   waves 4-7 (kh=1): h-half (ic 64..127)
// Per step: P0 [x-GEMM || spin+h-load+h-stage]; #1; P1 [partials+x(t+1)-stage || h-GEMM];
//           #2; P2 [gates + write-through stores + flag release].
// Weights: 12 KB/block via block-uniform s_load (fits 16 KB scalar cache).
// cat [258][128] fp32 XOR-swizzled (+ part [8][256]) = 140 KB dynamic LDS.

constexpr int Bn    = 8;
constexpr int Tn    = 128;
constexpr int CINn  = 64;
constexpr int COUTn = 64;
constexpr int Hn    = 256;
constexpr int NFLAG = Bn * Tn * 32;                       // 32768 words
constexpr size_t LDS_BYTES = (size_t)(258 * 128 + 8 * 256) * 4;  // 140288

__device__ __forceinline__ float sigmoidf_(float v) {
    return 1.0f / (1.0f + __expf(-v));
}
__device__ __forceinline__ float load_thru(const float* p) {
    return __hip_atomic_load(p, __ATOMIC_RELAXED, __HIP_MEMORY_SCOPE_SYSTEM);
}
__device__ __forceinline__ void store_thru(float* p, float v) {
    __hip_atomic_store(p, v, __ATOMIC_RELAXED, __HIP_MEMORY_SCOPE_SYSTEM);
}

template <bool USE_FLAGS>
__global__ __launch_bounds__(512, 2) void convlstm_persist(
    const float* __restrict__ x,     // [B][T][CIN][H]
    const float* __restrict__ h0,    // [B][COUT][H]
    const float* __restrict__ c0,    // [B][COUT][H]
    const float* __restrict__ wg,    // [4*COUT][128][3]
    const float* __restrict__ bias,  // [4*COUT]
    const float* __restrict__ wci,   // [COUT][H]
    const float* __restrict__ wcf,   // [COUT][H]
    const float* __restrict__ wco,   // [COUT][H]
    float* __restrict__ hs,          // [B][T][COUT][H]
    float* __restrict__ cs,          // [B][T][COUT][H]
    unsigned int* flags)             // [B][T][32]
{
    extern __shared__ float lds[];
    float*  cat  = lds;                         // [258][128] swizzled
    float*  part = lds + 258 * 128;             // [8][256]
    float4* cat4 = (float4*)cat;

    const int tid = threadIdx.x;
    const int blk = blockIdx.x;
    const int b   = blk & 7;                    // all coz of batch b -> one XCD
    const int coz = blk >> 3;                   // 0..31
    const int co0 = coz * 2;
    const int kh  = tid >> 8;                   // 0 = x-waves, 1 = h-waves
    const int p_l = tid & 255;

    const int row = p_l + 1;
    const int rs  = row & 31;

    // halo rows 0 / 257 (p=-1, p=256): zero, t-invariant
    if (tid < 32)       cat4[tid] = make_float4(0.f, 0.f, 0.f, 0.f);
    else if (tid < 64)  cat4[257 * 32 + (tid - 32)] = make_float4(0.f, 0.f, 0.f, 0.f);

    // persistent per-thread state
    float bias_r[8];
#pragma unroll
    for (int k = 0; k < 8; ++k)
        bias_r[k] = bias[(k >> 1) * COUTn + co0 + (k & 1)];

    float c_reg[2] = {0.f, 0.f}, wci_r[2], wcf_r[2], wco_r[2];
    if (kh == 1) {
#pragma unroll
        for (int j = 0; j < 2; ++j) {
            const int cidx = (co0 + j) * Hn + p_l;
            wci_r[j] = wci[cidx];
            wcf_r[j] = wcf[cidx];
            wco_r[j] = wco[cidx];
            c_reg[j] = c0[b * COUTn * Hn + cidx];
        }
    }

    const float4* __restrict__ w4 = (const float4*)wg;   // block-uniform

    cg::grid_group grid = cg::this_grid();

    // ---- staging helpers ----
    auto stage_x = [&](const float* src) {               // quads 0..15, cached
#pragma unroll
        for (int g16 = 0; g16 < 4; ++g16) {
            float tmp[16];
#pragma unroll
            for (int i = 0; i < 16; ++i)
                tmp[i] = src[(g16 * 16 + i) * Hn + p_l];
#pragma unroll
            for (int ii = 0; ii < 4; ++ii)
                cat4[row * 32 + ((g16 * 4 + ii) ^ rs)] =
                    make_float4(tmp[4 * ii], tmp[4 * ii + 1],
                                tmp[4 * ii + 2], tmp[4 * ii + 3]);
        }
    };
    auto stage_h = [&](const float* src) {               // quads 16..31, sc-bypass
#pragma unroll
        for (int g16 = 0; g16 < 4; ++g16) {
            float tmp[16];
#pragma unroll
            for (int i = 0; i < 16; ++i)
                tmp[i] = load_thru(src + (g16 * 16 + i) * Hn + p_l);
#pragma unroll
            for (int ii = 0; ii < 4; ++ii)
                cat4[row * 32 + ((16 + g16 * 4 + ii) ^ rs)] =
                    make_float4(tmp[4 * ii], tmp[4 * ii + 1],
                                tmp[4 * ii + 2], tmp[4 * ii + 3]);
        }
    };
    auto gemm_half = [&](int q0, float* acc) {           // 16 quads starting q0
        const int r0 = p_l, r1 = p_l + 1, r2 = p_l + 2;
        const int s0 = r0 & 31, s1 = r1 & 31, s2 = r2 & 31;
#pragma unroll 2
        for (int icq = q0; icq < q0 + 16; ++icq) {
            const float4 a0 = cat4[r0 * 32 + (icq ^ s0)];
            const float4 a1 = cat4[r1 * 32 + (icq ^ s1)];
            const float4 a2 = cat4[r2 * 32 + (icq ^ s2)];
            const float in0[4] = {a0.x, a0.y, a0.z, a0.w};
            const float in1[4] = {a1.x, a1.y, a1.z, a1.w};
            const float in2[4] = {a2.x, a2.y, a2.z, a2.w};
#pragma unroll
            for (int k = 0; k < 8; ++k) {
                const int wrow = (k >> 1) * COUTn + co0 + (k & 1);
                const float4 w0 = w4[(size_t)wrow * 96 + icq * 3 + 0];
                const float4 w1 = w4[(size_t)wrow * 96 + icq * 3 + 1];
                const float4 w2 = w4[(size_t)wrow * 96 + icq * 3 + 2];
                const float wr_[12] = {w0.x, w0.y, w0.z, w0.w,
                                       w1.x, w1.y, w1.z, w1.w,
                                       w2.x, w2.y, w2.z, w2.w};
#pragma unroll
                for (int i = 0; i < 4; ++i) {
                    acc[k] = fmaf(wr_[3 * i + 0], in0[i],
                              fmaf(wr_[3 * i + 1], in1[i],
                              fmaf(wr_[3 * i + 2], in2[i], acc[k])));
                }
            }
        }
    };

    // ---- prologue: stage x_0 ----
    if (kh == 0) stage_x(x + (size_t)(b * Tn + 0) * CINn * Hn);
    __syncthreads();

    for (int t = 0; t < Tn; ++t) {
        float acc[8];

        // ======== P0: x-GEMM  ||  spin + h-load + h-stage ========
        if (kh == 0) {
#pragma unroll
            for (int k = 0; k < 8; ++k) acc[k] = bias_r[k];
            gemm_half(0, acc);
        } else {
            if (USE_FLAGS && t > 0) {
                const unsigned int* fp =
                    flags + (size_t)(b * Tn + (t - 1)) * 32 + (tid & 31);
                while (true) {
                    unsigned int v = __hip_atomic_load(fp, __ATOMIC_RELAXED,
                                                       __HIP_MEMORY_SCOPE_SYSTEM);
                    if (__all(v >= 4u)) break;
                    __builtin_amdgcn_s_sleep(2);
                }
            }
            const float* hp = (t == 0)
                ? (h0 + (size_t)b * COUTn * Hn)
                : (hs + (size_t)(b * Tn + (t - 1)) * COUTn * Hn);
            stage_h(hp);
        }
        __syncthreads();   // #1

        // ======== P1: partials + x(t+1) prefetch-stage  ||  h-GEMM ========
        if (kh == 0) {
#pragma unroll
            for (int k = 0; k < 8; ++k) part[k * Hn + p_l] = acc[k];
            if (t + 1 < Tn)
                stage_x(x + (size_t)(b * Tn + (t + 1)) * CINn * Hn);
        } else {
#pragma unroll
            for (int k = 0; k < 8; ++k) acc[k] = 0.f;
            gemm_half(16, acc);
        }
        __syncthreads();   // #2

        // ======== P2: gates + stores + flag release (h-waves) ========
        if (kh == 1) {
#pragma unroll
            for (int j = 0; j < 2; ++j) {
                const float pi  = part[(0 + j) * Hn + p_l] + acc[0 + j];
                const float pf  = part[(2 + j) * Hn + p_l] + acc[2 + j];
                const float pgv = part[(4 + j) * Hn + p_l] + acc[4 + j];
                const float po  = part[(6 + j) * Hn + p_l] + acc[6 + j];

                const float cprev = c_reg[j];
                const float iv = sigmoidf_(pi + wci_r[j] * cprev);
                const float fv = sigmoidf_(pf + wcf_r[j] * cprev);
                const float gv = tanhf(pgv);
                const float cn = fv * cprev + iv * gv;
                const float ov = sigmoidf_(po + wco_r[j] * cn);
                const float hn = ov * tanhf(cn);
                c_reg[j] = cn;

                const size_t oidx =
                    ((size_t)(b * Tn + t) * COUTn + co0 + j) * Hn + p_l;
                store_thru(hs + oidx, hn);
                store_thru(cs + oidx, cn);
            }
            if (USE_FLAGS) {
                if ((tid & 63) == 0) {
                    // release: drains this wave's stores to the coherence
                    // point before the count becomes visible
                    __hip_atomic_fetch_add(
                        flags + (size_t)(b * Tn + t) * 32 + coz, 1u,
                        __ATOMIC_RELEASE, __HIP_MEMORY_SCOPE_SYSTEM);
                }
            }
        }
        if (!USE_FLAGS) {
            __threadfence();
            grid.sync();
        }
    }
}

__global__ __launch_bounds__(256) void zero_flags(unsigned int* f, int n) {
    const int i = blockIdx.x * 256 + threadIdx.x;
    if (i < n)
        __hip_atomic_store(&f[i], 0u, __ATOMIC_RELAXED, __HIP_MEMORY_SCOPE_SYSTEM);
}

extern "C" void kernel_launch(void* const* d_in, const int* in_sizes, int n_in,
                              void* d_out, int out_size, void* d_ws, size_t ws_size,
                              hipStream_t stream) {
    (void)in_sizes; (void)n_in; (void)out_size;

    const float* x    = (const float*)d_in[0];
    const float* h0   = (const float*)d_in[1];
    const float* c0   = (const float*)d_in[2];
    const float* w    = (const float*)d_in[3];
    const float* bias = (const float*)d_in[4];
    const float* wci  = (const float*)d_in[5];
    const float* wcf  = (const float*)d_in[6];
    const float* wco  = (const float*)d_in[7];

    float* hs = (float*)d_out;
    float* cs = hs + (size_t)Bn * Tn * COUTn * Hn;
    unsigned int* flags = (unsigned int*)d_ws;

    const size_t flag_bytes = (size_t)NFLAG * sizeof(unsigned int);  // 128 KB
    const bool use_flags = (d_ws != nullptr) && (ws_size >= flag_bytes);

    void* args[] = {(void*)&x, (void*)&h0, (void*)&c0, (void*)&w,
                    (void*)&bias, (void*)&wci, (void*)&wcf, (void*)&wco,
                    (void*)&hs, (void*)&cs, (void*)&flags};

    if (use_flags) {
        hipFuncSetAttribute((const void*)convlstm_persist<true>,
                            hipFuncAttributeMaxDynamicSharedMemorySize,
                            (int)LDS_BYTES);
        zero_flags<<<(NFLAG + 255) / 256, 256, 0, stream>>>(flags, NFLAG);
        hipLaunchCooperativeKernel((const void*)convlstm_persist<true>,
                                   dim3(256), dim3(512), args,
                                   (unsigned int)LDS_BYTES, stream);
    } else {
        hipFuncSetAttribute((const void*)convlstm_persist<false>,
                            hipFuncAttributeMaxDynamicSharedMemorySize,
                            (int)LDS_BYTES);
        hipLaunchCooperativeKernel((const void*)convlstm_persist<false>,
                                   dim3(256), dim3(512), args,
                                   (unsigned int)LDS_BYTES, stream);
    }
}